// Round 4
// baseline (284.179 us; speedup 1.0000x reference)
//
#include <hip/hip_runtime.h>

#define EPS 1e-3f

// x: [16,56,56,128], out: [16,28,28,256], G=32 groups, BF=4
#define NPIX   50176   // 16*56*56
#define NOPIX  12544   // 16*28*28

// ws float offsets
#define OFF_ST1  0        // [32][128][2] interleaved (s,t) for bn1
#define OFF_S2   8192     // [32][4]
#define OFF_T2   8320
#define OFF_T3   8576     // [128]
#define OFF_BSUM 8704     // [256]
#define OFF_W3S  8960     // [32 g][4 f][9 kk][4 ci], f-major, pre-scaled by s3
#define OFF_V    13568    // [4 gc][12544 opx][32 kk] fp32

__global__ __launch_bounds__(256)
void prep_kernel(const float* __restrict__ g1, const float* __restrict__ be1,
                 const float* __restrict__ m1, const float* __restrict__ v1,
                 const float* __restrict__ b1, const float* __restrict__ g2,
                 const float* __restrict__ be2, const float* __restrict__ m2,
                 const float* __restrict__ v2, const float* __restrict__ W3,
                 const float* __restrict__ b3, const float* __restrict__ g3,
                 const float* __restrict__ be3, const float* __restrict__ m3,
                 const float* __restrict__ v3, const float* __restrict__ b2,
                 float* __restrict__ ws) {
    int gid = blockIdx.x * 256 + threadIdx.x;
    int stride = gridDim.x * 256;
    for (int i = gid; i < 4096; i += stride) {
        float s = g1[i] * rsqrtf(v1[i] + EPS);
        float t = be1[i] - m1[i] * s;
        ws[OFF_ST1 + 2*i]     = s;
        ws[OFF_ST1 + 2*i + 1] = t;
    }
    // W3 re-laid f-major and pre-scaled by s3: [g][f][kk][ci]
    for (int i = gid; i < 4608; i += stride) {
        int g = i / 144, rem = i - g*144;
        int f = rem / 36, rem2 = rem - f*36;
        int kk = rem2 >> 2, ci = rem2 & 3;
        int k = g*4 + f;
        float s3 = g3[k] * rsqrtf(v3[k] + EPS);
        ws[OFF_W3S + i] = W3[g*144 + kk*16 + ci*4 + f] * s3;
    }
    if (gid < 128) {
        float s2 = g2[gid] * rsqrtf(v2[gid] + EPS);
        ws[OFF_S2 + gid] = s2;
        ws[OFF_T2 + gid] = be2[gid] + (b1[gid] - m2[gid]) * s2;
        float s3 = g3[gid] * rsqrtf(v3[gid] + EPS);
        ws[OFF_T3 + gid] = be3[gid] + (b3[gid] - m3[gid]) * s3;
    } else if (gid >= 256 && gid < 512) {
        int co = gid - 256;
        float acc = 0.f;
        for (int g = 0; g < 32; ++g) acc += b2[g*256 + co];
        ws[OFF_BSUM + co] = acc;
    }
}

// Fused stage1 + 3x3 stride-2 conv. Grid = 16 b x 7 row-stripes x 4 gchunks.
// Block 512 thr: stage1 thread<->input px (9 rows x 56 cols = 504), all 8
// groups of the chunk accumulated in regs with wave-uniform scalar table
// loads; then per group: bn2 -> us (LDS) -> conv -> v slice (LDS) -> global.
__global__ __launch_bounds__(512)
void fusedA_kernel(const float* __restrict__ x,
                   const float* __restrict__ W1,     // [32,128,4]
                   const float* __restrict__ tabs,   // ws
                   float* __restrict__ vout) {       // ws + OFF_V
    __shared__ float us[504 * 4];     // one group's U tile [px][ci]
    __shared__ float vs[112 * 33];    // [opx][32 k-slice], padded
    __shared__ float w3sh[1152];      // [8 gi][4 f][9 kk][4 ci]
    __shared__ float t3sh[32];
    int tid = threadIdx.x;
    int gc = blockIdx.x & 3;
    int rest = blockIdx.x >> 2;
    int t = rest % 7, b = rest / 7;

    for (int i = tid; i < 1152; i += 512) w3sh[i] = tabs[OFF_W3S + gc*1152 + i];
    if (tid < 32) t3sh[tid] = tabs[OFF_T3 + gc*32 + tid];

    // ---- stage 1: this thread's input pixel, 8 groups ----
    int r = tid / 56;
    int c = tid - r*56;
    int ih = 8*t - 1 + r;                    // r=0 row is pad only when t==0
    bool inb = (tid < 504) && (ih >= 0);

    float acc[8][4];
    #pragma unroll
    for (int gi = 0; gi < 8; ++gi)
        acc[gi][0] = acc[gi][1] = acc[gi][2] = acc[gi][3] = 0.f;

    if (inb) {
        const float4* xb = (const float4*)(x + ((size_t)((b*56 + ih)*56 + c)) * 128);
        #pragma unroll 1
        for (int cc = 0; cc < 4; ++cc) {
            float xr[32];
            #pragma unroll
            for (int j = 0; j < 8; ++j) *(float4*)&xr[4*j] = xb[cc*8 + j];
            #pragma unroll
            for (int gi = 0; gi < 8; ++gi) {
                int g = gc*8 + gi;
                const float2* st = (const float2*)(tabs + OFF_ST1) + (g*128 + cc*32);
                const float4* w1 = (const float4*)W1 + (g*128 + cc*32);
                #pragma unroll 8
                for (int k = 0; k < 32; ++k) {
                    float2 s = st[k];          // uniform -> s_load
                    float4 w = w1[k];          // uniform -> s_load
                    float z = fmaxf(fmaf(xr[k], s.x, s.y), 0.f);
                    acc[gi][0] = fmaf(z, w.x, acc[gi][0]);
                    acc[gi][1] = fmaf(z, w.y, acc[gi][1]);
                    acc[gi][2] = fmaf(z, w.z, acc[gi][2]);
                    acc[gi][3] = fmaf(z, w.w, acc[gi][3]);
                }
            }
        }
    }

    // ---- per-group: bn2 -> us, conv -> vs ----
    int f = tid & 3, opx = tid >> 2;         // conv mapping: 112 opx x 4 f
    int orr = opx / 28, oc = opx - orr*28;
    bool cact = tid < 448;

    #pragma unroll 1
    for (int gi = 0; gi < 8; ++gi) {
        int g = gc*8 + gi;
        __syncthreads();                      // prior conv reads done
        if (tid < 504) {
            float4 s2v = ((const float4*)(tabs + OFF_S2))[g];
            float4 t2v = ((const float4*)(tabs + OFF_T2))[g];
            float4 u;
            u.x = inb ? fmaxf(fmaf(acc[gi][0], s2v.x, t2v.x), 0.f) : 0.f;
            u.y = inb ? fmaxf(fmaf(acc[gi][1], s2v.y, t2v.y), 0.f) : 0.f;
            u.z = inb ? fmaxf(fmaf(acc[gi][2], s2v.z, t2v.z), 0.f) : 0.f;
            u.w = inb ? fmaxf(fmaf(acc[gi][3], s2v.w, t2v.w), 0.f) : 0.f;
            *(float4*)&us[tid * 4] = u;
        }
        __syncthreads();
        if (cact) {
            float a = 0.f;
            #pragma unroll
            for (int kh = 0; kh < 3; ++kh) {
                int rr2 = 2*orr + kh;          // 0..8, always in range
                #pragma unroll
                for (int kw = 0; kw < 3; ++kw) {
                    int ic = 2*oc - 1 + kw;    // -1..55; skip left pad
                    if (ic < 0) continue;
                    float4 u  = *(const float4*)&us[(rr2*56 + ic) * 4];
                    float4 wv = *(const float4*)&w3sh[gi*144 + f*36 + (kh*3 + kw)*4];
                    a = fmaf(u.x, wv.x, a);
                    a = fmaf(u.y, wv.y, a);
                    a = fmaf(u.z, wv.z, a);
                    a = fmaf(u.w, wv.w, a);
                }
            }
            float v = fmaxf(a + t3sh[gi*4 + f], 0.f);
            vs[opx*33 + gi*4 + f] = v;
        }
    }
    __syncthreads();

    // ---- coalesced v-slice store: [gc][block px range][32] ----
    float* vg = vout + (size_t)gc * 401408 + (size_t)(b*7 + t) * 3584;
    for (int i = tid; i < 3584; i += 512)
        vg[i] = vs[(i >> 5)*33 + (i & 31)];
}

// Final GEMM: out[opx, co] = sum_k v[opx][k]*W2[k][co] + bsum[co] + res[opx]
// Block 256 thr = 256 co, 16 px; v read via block-uniform s_loads.
__global__ __launch_bounds__(256)
void fusedB_kernel(const float* __restrict__ x,
                   const float* __restrict__ W2,     // [128,256]
                   const float* __restrict__ tabs,   // ws
                   const float* __restrict__ vin,    // ws + OFF_V
                   float* __restrict__ out) {
    __shared__ float res_s[16];
    int tid = threadIdx.x;
    int opxBase = blockIdx.x * 16;
    {
        int p = tid >> 4, l = tid & 15;
        int op = opxBase + p;
        int bb = op / 784, rr = op - bb*784;
        int oh = rr / 28, ow = rr - oh*28;
        const float* xp = x + ((size_t)((bb*56 + 2*oh)*56 + 2*ow)) * 128;
        float rv = 0.f;
        #pragma unroll
        for (int j = 0; j < 8; ++j) rv += xp[l + 16*j];
        #pragma unroll
        for (int off = 8; off; off >>= 1) rv += __shfl_down(rv, off, 16);
        if (l == 0) res_s[p] = rv;
    }
    __syncthreads();

    int co = tid;
    float bs = tabs[OFF_BSUM + co];
    float acc[16];
    #pragma unroll
    for (int q = 0; q < 16; ++q) acc[q] = bs;

    #pragma unroll 1
    for (int k = 0; k < 128; k += 4) {
        int gc2 = k >> 5, kk = k & 31;
        const float* vb = vin + (size_t)gc2 * 401408 + (size_t)opxBase * 32 + kk;
        float w0 = W2[(k+0)*256 + co];
        float w1 = W2[(k+1)*256 + co];
        float w2v = W2[(k+2)*256 + co];
        float w3v = W2[(k+3)*256 + co];
        #pragma unroll
        for (int q = 0; q < 16; ++q) {
            float4 v = *(const float4*)(vb + q*32);   // uniform -> s_load_x4
            acc[q] = fmaf(v.x, w0, acc[q]);
            acc[q] = fmaf(v.y, w1, acc[q]);
            acc[q] = fmaf(v.z, w2v, acc[q]);
            acc[q] = fmaf(v.w, w3v, acc[q]);
        }
    }
    #pragma unroll
    for (int q = 0; q < 16; ++q)
        out[(size_t)(opxBase + q)*256 + co] = acc[q] + res_s[q];
}

extern "C" void kernel_launch(void* const* d_in, const int* in_sizes, int n_in,
                              void* d_out, int out_size, void* d_ws, size_t ws_size,
                              hipStream_t stream) {
    const float* x   = (const float*)d_in[0];
    const float* g1  = (const float*)d_in[1];
    const float* be1 = (const float*)d_in[2];
    const float* m1  = (const float*)d_in[3];
    const float* v1  = (const float*)d_in[4];
    const float* W1  = (const float*)d_in[5];
    const float* b1  = (const float*)d_in[6];
    const float* g2  = (const float*)d_in[7];
    const float* be2 = (const float*)d_in[8];
    const float* m2  = (const float*)d_in[9];
    const float* v2  = (const float*)d_in[10];
    const float* W3  = (const float*)d_in[11];
    const float* b3  = (const float*)d_in[12];
    const float* g3  = (const float*)d_in[13];
    const float* be3 = (const float*)d_in[14];
    const float* m3  = (const float*)d_in[15];
    const float* v3  = (const float*)d_in[16];
    const float* W2  = (const float*)d_in[17];
    const float* b2  = (const float*)d_in[18];
    float* out = (float*)d_out;
    float* ws  = (float*)d_ws;

    prep_kernel<<<32, 256, 0, stream>>>(g1, be1, m1, v1, b1, g2, be2, m2, v2,
                                        W3, b3, g3, be3, m3, v3, b2, ws);
    fusedA_kernel<<<448, 512, 0, stream>>>(x, W1, ws, ws + OFF_V);
    fusedB_kernel<<<NOPIX / 16, 256, 0, stream>>>(x, W2, ws, ws + OFF_V, out);
}

// Round 5
// 237.670 us; speedup vs baseline: 1.1957x; 1.1957x over previous
//
#include <hip/hip_runtime.h>

#define EPS 1e-3f
#define NPIX  50176   // 16*56*56
#define NOPIX 12544   // 16*28*28

// ws float offsets
#define OFF_ST1  0        // [32][128][2] (s,t) for bn1
#define OFF_S2   8192     // [32][4]
#define OFF_T2   8320     // [32][4]
#define OFF_T3   8448     // [128]
#define OFF_BSUM 8576     // [256]
#define OFF_W3S  8832     // [32 g][4 f][9 kk][4 ci] pre-scaled by s3
#define OFF_U    13440    // [784 pxblk][32 g][64 px] float4

__global__ __launch_bounds__(256)
void prep_kernel(const float* __restrict__ g1, const float* __restrict__ be1,
                 const float* __restrict__ m1, const float* __restrict__ v1,
                 const float* __restrict__ b1, const float* __restrict__ g2,
                 const float* __restrict__ be2, const float* __restrict__ m2,
                 const float* __restrict__ v2, const float* __restrict__ W3,
                 const float* __restrict__ b3, const float* __restrict__ g3,
                 const float* __restrict__ be3, const float* __restrict__ m3,
                 const float* __restrict__ v3, const float* __restrict__ b2,
                 float* __restrict__ ws) {
    int gid = blockIdx.x * 256 + threadIdx.x;
    int stride = gridDim.x * 256;
    for (int i = gid; i < 4096; i += stride) {
        float s = g1[i] * rsqrtf(v1[i] + EPS);
        float t = be1[i] - m1[i] * s;
        ws[OFF_ST1 + 2*i]     = s;
        ws[OFF_ST1 + 2*i + 1] = t;
    }
    // W3 re-laid f-major, pre-scaled by s3: [g][f][kk][ci]
    for (int i = gid; i < 4608; i += stride) {
        int g = i / 144, rem = i - g*144;
        int f = rem / 36, rem2 = rem - f*36;
        int kk = rem2 >> 2, ci = rem2 & 3;
        int k = g*4 + f;
        float s3 = g3[k] * rsqrtf(v3[k] + EPS);
        ws[OFF_W3S + i] = W3[g*144 + kk*16 + ci*4 + f] * s3;
    }
    if (gid < 128) {
        float s2 = g2[gid] * rsqrtf(v2[gid] + EPS);
        ws[OFF_S2 + gid] = s2;
        ws[OFF_T2 + gid] = be2[gid] + (b1[gid] - m2[gid]) * s2;
        float s3 = g3[gid] * rsqrtf(v3[gid] + EPS);
        ws[OFF_T3 + gid] = be3[gid] + (b3[gid] - m3[gid]) * s3;
    } else if (gid >= 256 && gid < 512) {
        int co = gid - 256;
        float acc = 0.f;
        for (int g = 0; g < 32; ++g) acc += b2[g*256 + co];
        ws[OFF_BSUM + co] = acc;
    }
}

// Stage 1: block 256 = 4 waves, wave = same 64 px; 2 passes x 4 groups/wave
// (acc[4][4]=16 regs, xr[16] per 16-ch chunk -> no spills). Tables via
// wave-uniform scalar loads. U stored [pxblk][g][lane][4f]: dense 4KB bursts.
__global__ __launch_bounds__(256)
void stage1_kernel(const float* __restrict__ x,
                   const float* __restrict__ W1,     // [32,128,4]
                   const float* __restrict__ tabs,   // ws
                   float* __restrict__ uout) {       // ws + OFF_U
    __shared__ float4 xs4[2048];                     // 32 KB, XOR-swizzled
    int tid = threadIdx.x;
    const float4* xg = (const float4*)x + (size_t)blockIdx.x * 2048;
    for (int i = tid; i < 2048; i += 256) {
        int p = i >> 5, f4 = i & 31;
        xs4[p*32 + (f4 ^ (p & 31))] = xg[i];
    }
    __syncthreads();

    int lane = tid & 63;
    int wbase = __builtin_amdgcn_readfirstlane(tid >> 6) * 4;
    float4* U4 = (float4*)uout;
    size_t ubase = (size_t)blockIdx.x * 32;

    #pragma unroll 1
    for (int pass = 0; pass < 2; ++pass) {
        float acc[4][4];
        #pragma unroll
        for (int gi = 0; gi < 4; ++gi)
            acc[gi][0] = acc[gi][1] = acc[gi][2] = acc[gi][3] = 0.f;

        #pragma unroll 1
        for (int ch = 0; ch < 8; ++ch) {
            float xr[16];
            #pragma unroll
            for (int j = 0; j < 4; ++j)
                *(float4*)&xr[4*j] = xs4[lane*32 + ((4*ch + j) ^ (lane & 31))];
            #pragma unroll
            for (int gi = 0; gi < 4; ++gi) {
                int g = pass*16 + wbase + gi;
                const float2* st = (const float2*)(tabs + OFF_ST1) + g*128 + ch*16;
                const float4* w1 = (const float4*)W1 + g*128 + ch*16;
                #pragma unroll
                for (int c = 0; c < 16; ++c) {
                    float2 s = st[c];          // uniform -> s_load
                    float4 w = w1[c];          // uniform -> s_load
                    float z = fmaxf(fmaf(xr[c], s.x, s.y), 0.f);
                    acc[gi][0] = fmaf(z, w.x, acc[gi][0]);
                    acc[gi][1] = fmaf(z, w.y, acc[gi][1]);
                    acc[gi][2] = fmaf(z, w.z, acc[gi][2]);
                    acc[gi][3] = fmaf(z, w.w, acc[gi][3]);
                }
            }
        }
        #pragma unroll
        for (int gi = 0; gi < 4; ++gi) {
            int g = pass*16 + wbase + gi;
            float4 s2v = ((const float4*)(tabs + OFF_S2))[g];
            float4 t2v = ((const float4*)(tabs + OFF_T2))[g];
            float4 u;
            u.x = fmaxf(fmaf(acc[gi][0], s2v.x, t2v.x), 0.f);
            u.y = fmaxf(fmaf(acc[gi][1], s2v.y, t2v.y), 0.f);
            u.z = fmaxf(fmaf(acc[gi][2], s2v.z, t2v.z), 0.f);
            u.w = fmaxf(fmaf(acc[gi][3], s2v.w, t2v.w), 0.f);
            U4[(ubase + g)*64 + lane] = u;     // dense 4 KB per wave-store
        }
    }
}

// Stage 2: block = 32 opx. Conv threads (tid<128) + residual threads
// (tid>=128) run concurrently; then phase-B GEMM (thread = 4 co x 8 opx).
__global__ __launch_bounds__(256)
void stage2_kernel(const float* __restrict__ x,
                   const float* __restrict__ W2,     // [128,256]
                   const float* __restrict__ tabs,   // ws
                   const float* __restrict__ U,      // ws + OFF_U
                   float* __restrict__ out) {
    __shared__ float w3s[4608];
    __shared__ float t3s[128];
    __shared__ float vs[32 * 132];
    __shared__ float res_s[32];
    int tid = threadIdx.x;
    for (int i = tid; i < 4608; i += 256) w3s[i] = tabs[OFF_W3S + i];
    if (tid < 128) t3s[tid] = tabs[OFF_T3 + tid];
    __syncthreads();

    int opxBase = blockIdx.x * 32;
    if (tid < 128) {
        // ---- 3x3 stride-2 conv: thread = (opx_l, f), loop g ----
        int opx_l = tid >> 2, f = tid & 3;
        int opx = opxBase + opx_l;
        int b = opx / 784, r = opx - b*784;
        int oh = r / 28, ow = r - oh*28;
        const float4* U4 = (const float4*)U;
        #pragma unroll 1
        for (int g = 0; g < 32; ++g) {
            float a = 0.f;
            #pragma unroll
            for (int kh = 0; kh < 3; ++kh) {
                int ih = 2*oh - 1 + kh;
                if (ih < 0) continue;
                #pragma unroll
                for (int kw = 0; kw < 3; ++kw) {
                    int ic = 2*ow - 1 + kw;
                    if (ic < 0) continue;
                    int px = (b*56 + ih)*56 + ic;
                    float4 u = U4[((size_t)(px >> 6)*32 + g)*64 + (px & 63)];
                    float4 wv = *(const float4*)&w3s[g*144 + f*36 + (kh*3 + kw)*4];
                    a = fmaf(u.x, wv.x, a);
                    a = fmaf(u.y, wv.y, a);
                    a = fmaf(u.z, wv.z, a);
                    a = fmaf(u.w, wv.w, a);
                }
            }
            vs[opx_l*132 + g*4 + f] = fmaxf(a + t3s[g*4 + f], 0.f);
        }
    } else {
        // ---- residual: res[p] = sum_c x[b, 2oh, 2ow, c] ----
        int idx = tid - 128;
        int p = idx >> 2, l = idx & 3;
        int opx = opxBase + p;
        int b = opx / 784, r = opx - b*784;
        int oh = r / 28, ow = r - oh*28;
        const float4* xp = (const float4*)(x + (size_t)((b*56 + 2*oh)*56 + 2*ow) * 128);
        float rv = 0.f;
        #pragma unroll
        for (int j = 0; j < 8; ++j) {
            float4 v = xp[l + 4*j];
            rv += v.x + v.y + v.z + v.w;
        }
        rv += __shfl_down(rv, 2, 4);
        rv += __shfl_down(rv, 1, 4);
        if (l == 0) res_s[p] = rv;
    }
    __syncthreads();

    // ---- phase B: out[opx][co] = vs @ W2 + bsum + res ----
    int w = tid >> 6, l = tid & 63;
    int qBase = w * 8;
    float4 bs = *(const float4*)(tabs + OFF_BSUM + 4*l);
    float acc[8][4];
    #pragma unroll
    for (int q = 0; q < 8; ++q) {
        acc[q][0] = bs.x; acc[q][1] = bs.y; acc[q][2] = bs.z; acc[q][3] = bs.w;
    }
    const float* W2c = W2 + 4*l;
    #pragma unroll 1
    for (int k4 = 0; k4 < 32; ++k4) {
        float4 wr0 = *(const float4*)(W2c + (k4*4 + 0)*256);
        float4 wr1 = *(const float4*)(W2c + (k4*4 + 1)*256);
        float4 wr2 = *(const float4*)(W2c + (k4*4 + 2)*256);
        float4 wr3 = *(const float4*)(W2c + (k4*4 + 3)*256);
        #pragma unroll
        for (int q = 0; q < 8; ++q) {
            float4 v = *(const float4*)&vs[(qBase + q)*132 + k4*4];  // broadcast
            acc[q][0] = fmaf(v.x, wr0.x, acc[q][0]);
            acc[q][1] = fmaf(v.x, wr0.y, acc[q][1]);
            acc[q][2] = fmaf(v.x, wr0.z, acc[q][2]);
            acc[q][3] = fmaf(v.x, wr0.w, acc[q][3]);
            acc[q][0] = fmaf(v.y, wr1.x, acc[q][0]);
            acc[q][1] = fmaf(v.y, wr1.y, acc[q][1]);
            acc[q][2] = fmaf(v.y, wr1.z, acc[q][2]);
            acc[q][3] = fmaf(v.y, wr1.w, acc[q][3]);
            acc[q][0] = fmaf(v.z, wr2.x, acc[q][0]);
            acc[q][1] = fmaf(v.z, wr2.y, acc[q][1]);
            acc[q][2] = fmaf(v.z, wr2.z, acc[q][2]);
            acc[q][3] = fmaf(v.z, wr2.w, acc[q][3]);
            acc[q][0] = fmaf(v.w, wr3.x, acc[q][0]);
            acc[q][1] = fmaf(v.w, wr3.y, acc[q][1]);
            acc[q][2] = fmaf(v.w, wr3.z, acc[q][2]);
            acc[q][3] = fmaf(v.w, wr3.w, acc[q][3]);
        }
    }
    #pragma unroll
    for (int q = 0; q < 8; ++q) {
        float rq = res_s[qBase + q];
        float4 o;
        o.x = acc[q][0] + rq; o.y = acc[q][1] + rq;
        o.z = acc[q][2] + rq; o.w = acc[q][3] + rq;
        *(float4*)(out + (size_t)(opxBase + qBase + q)*256 + 4*l) = o;
    }
}

extern "C" void kernel_launch(void* const* d_in, const int* in_sizes, int n_in,
                              void* d_out, int out_size, void* d_ws, size_t ws_size,
                              hipStream_t stream) {
    const float* x   = (const float*)d_in[0];
    const float* g1  = (const float*)d_in[1];
    const float* be1 = (const float*)d_in[2];
    const float* m1  = (const float*)d_in[3];
    const float* v1  = (const float*)d_in[4];
    const float* W1  = (const float*)d_in[5];
    const float* b1  = (const float*)d_in[6];
    const float* g2  = (const float*)d_in[7];
    const float* be2 = (const float*)d_in[8];
    const float* m2  = (const float*)d_in[9];
    const float* v2  = (const float*)d_in[10];
    const float* W3  = (const float*)d_in[11];
    const float* b3  = (const float*)d_in[12];
    const float* g3  = (const float*)d_in[13];
    const float* be3 = (const float*)d_in[14];
    const float* m3  = (const float*)d_in[15];
    const float* v3  = (const float*)d_in[16];
    const float* W2  = (const float*)d_in[17];
    const float* b2  = (const float*)d_in[18];
    float* out = (float*)d_out;
    float* ws  = (float*)d_ws;

    prep_kernel<<<32, 256, 0, stream>>>(g1, be1, m1, v1, b1, g2, be2, m2, v2,
                                        W3, b3, g3, be3, m3, v3, b2, ws);
    stage1_kernel<<<NPIX / 64, 256, 0, stream>>>(x, W1, ws, ws + OFF_U);
    stage2_kernel<<<NOPIX / 32, 256, 0, stream>>>(x, W2, ws, ws + OFF_U, out);
}

// Round 6
// 188.021 us; speedup vs baseline: 1.5114x; 1.2641x over previous
//
#include <hip/hip_runtime.h>

#define EPS 1e-3f
#define NPIX  50176   // 16*56*56
#define NOPIX 12544   // 16*28*28

// ws float offsets
#define OFF_ST1  0        // [32][128][2] (s,t) for bn1
#define OFF_S2   8192     // [32][4]
#define OFF_T2   8320     // [32][4]
#define OFF_T3   8448     // [128]
#define OFF_BSUM 8576     // [256]
#define OFF_W3S  8832     // [32 g][4 f][9 kk][4 ci] pre-scaled by s3
#define OFF_U    13440    // [32 g][50176 px] float4 (g-planar)

__global__ __launch_bounds__(256)
void prep_kernel(const float* __restrict__ g1, const float* __restrict__ be1,
                 const float* __restrict__ m1, const float* __restrict__ v1,
                 const float* __restrict__ b1, const float* __restrict__ g2,
                 const float* __restrict__ be2, const float* __restrict__ m2,
                 const float* __restrict__ v2, const float* __restrict__ W3,
                 const float* __restrict__ b3, const float* __restrict__ g3,
                 const float* __restrict__ be3, const float* __restrict__ m3,
                 const float* __restrict__ v3, const float* __restrict__ b2,
                 float* __restrict__ ws) {
    int gid = blockIdx.x * 256 + threadIdx.x;
    int stride = gridDim.x * 256;
    for (int i = gid; i < 4096; i += stride) {
        float s = g1[i] * rsqrtf(v1[i] + EPS);
        float t = be1[i] - m1[i] * s;
        ws[OFF_ST1 + 2*i]     = s;
        ws[OFF_ST1 + 2*i + 1] = t;
    }
    // W3 re-laid f-major, pre-scaled by s3: [g][f][kk][ci]
    for (int i = gid; i < 4608; i += stride) {
        int g = i / 144, rem = i - g*144;
        int f = rem / 36, rem2 = rem - f*36;
        int kk = rem2 >> 2, ci = rem2 & 3;
        int k = g*4 + f;
        float s3 = g3[k] * rsqrtf(v3[k] + EPS);
        ws[OFF_W3S + i] = W3[g*144 + kk*16 + ci*4 + f] * s3;
    }
    if (gid < 128) {
        float s2 = g2[gid] * rsqrtf(v2[gid] + EPS);
        ws[OFF_S2 + gid] = s2;
        ws[OFF_T2 + gid] = be2[gid] + (b1[gid] - m2[gid]) * s2;
        float s3 = g3[gid] * rsqrtf(v3[gid] + EPS);
        ws[OFF_T3 + gid] = be3[gid] + (b3[gid] - m3[gid]) * s3;
    } else if (gid >= 256 && gid < 512) {
        int co = gid - 256;
        float acc = 0.f;
        for (int g = 0; g < 32; ++g) acc += b2[g*256 + co];
        ws[OFF_BSUM + co] = acc;
    }
}

// Stage 1: block 512 = 8 waves over the same 64 px; wave w owns groups
// [4w,4w+4) in ONE pass (acc[4][4], xr[16] -> no spills). Tables via
// wave-uniform scalar loads. U stored g-planar: dense 1KB wave bursts.
__global__ __launch_bounds__(512)
void stage1_kernel(const float* __restrict__ x,
                   const float* __restrict__ W1,     // [32,128,4]
                   const float* __restrict__ tabs,   // ws
                   float* __restrict__ uout) {       // ws + OFF_U
    __shared__ float4 xs4[2048];                     // 32 KB, XOR-swizzled
    int tid = threadIdx.x;
    const float4* xg = (const float4*)x + (size_t)blockIdx.x * 2048;
    for (int i = tid; i < 2048; i += 512) {
        int p = i >> 5, f4 = i & 31;
        xs4[p*32 + (f4 ^ (p & 31))] = xg[i];
    }
    __syncthreads();

    int lane = tid & 63;
    int wbase = __builtin_amdgcn_readfirstlane(tid >> 6) * 4;   // 0..28

    float acc[4][4];
    #pragma unroll
    for (int gi = 0; gi < 4; ++gi)
        acc[gi][0] = acc[gi][1] = acc[gi][2] = acc[gi][3] = 0.f;

    #pragma unroll 1
    for (int ch = 0; ch < 8; ++ch) {
        float xr[16];
        #pragma unroll
        for (int j = 0; j < 4; ++j)
            *(float4*)&xr[4*j] = xs4[lane*32 + ((4*ch + j) ^ (lane & 31))];
        #pragma unroll
        for (int gi = 0; gi < 4; ++gi) {
            int g = wbase + gi;
            const float2* st = (const float2*)(tabs + OFF_ST1) + g*128 + ch*16;
            const float4* w1 = (const float4*)W1 + g*128 + ch*16;
            #pragma unroll
            for (int c = 0; c < 16; ++c) {
                float2 s = st[c];          // uniform -> s_load
                float4 w = w1[c];          // uniform -> s_load
                float z = fmaxf(fmaf(xr[c], s.x, s.y), 0.f);
                acc[gi][0] = fmaf(z, w.x, acc[gi][0]);
                acc[gi][1] = fmaf(z, w.y, acc[gi][1]);
                acc[gi][2] = fmaf(z, w.z, acc[gi][2]);
                acc[gi][3] = fmaf(z, w.w, acc[gi][3]);
            }
        }
    }

    float4* U4 = (float4*)uout;
    size_t pxIdx = (size_t)blockIdx.x * 64 + lane;
    #pragma unroll
    for (int gi = 0; gi < 4; ++gi) {
        int g = wbase + gi;
        float4 s2v = ((const float4*)(tabs + OFF_S2))[g];
        float4 t2v = ((const float4*)(tabs + OFF_T2))[g];
        float4 u;
        u.x = fmaxf(fmaf(acc[gi][0], s2v.x, t2v.x), 0.f);
        u.y = fmaxf(fmaf(acc[gi][1], s2v.y, t2v.y), 0.f);
        u.z = fmaxf(fmaf(acc[gi][2], s2v.z, t2v.z), 0.f);
        u.w = fmaxf(fmaf(acc[gi][3], s2v.w, t2v.w), 0.f);
        U4[(size_t)g * NPIX + pxIdx] = u;  // 1 KB contiguous per wave
    }
}

// Stage 2: block = 16 opx, 256 threads, grid 784.
// Conv: thread = (q=tid>>6, opx_l=(tid>>2)&15, f=tid&3), loop g in [8q,8q+8).
// Then residual, then GEMM: thread = (opx-quad = tid>>6, 4 co = 4*(tid&63)).
__global__ __launch_bounds__(256)
void stage2_kernel(const float* __restrict__ x,
                   const float* __restrict__ W2,     // [128,256]
                   const float* __restrict__ tabs,   // ws
                   const float* __restrict__ U,      // ws + OFF_U (g-planar)
                   float* __restrict__ out) {
    __shared__ float w3s[4608];
    __shared__ float t3s[128];
    __shared__ float vs[16 * 132];
    __shared__ float res_s[16];
    int tid = threadIdx.x;
    for (int i = tid; i < 4608; i += 256) w3s[i] = tabs[OFF_W3S + i];
    if (tid < 128) t3s[tid] = tabs[OFF_T3 + tid];
    __syncthreads();

    int opxBase = blockIdx.x * 16;
    // ---- 3x3 stride-2 conv ----
    {
        int q = tid >> 6, opx_l = (tid >> 2) & 15, f = tid & 3;
        int opx = opxBase + opx_l;
        int b = opx / 784, r = opx - b*784;
        int oh = r / 28, ow = r - oh*28;
        #pragma unroll 1
        for (int gi = 0; gi < 8; ++gi) {
            int g = q*8 + gi;
            const float4* Ug = (const float4*)U + (size_t)g * NPIX;
            const float* wg = w3s + g*144 + f*36;
            float a = 0.f;
            #pragma unroll
            for (int kh = 0; kh < 3; ++kh) {
                int ih = 2*oh - 1 + kh;
                if (ih < 0) continue;
                #pragma unroll
                for (int kw = 0; kw < 3; ++kw) {
                    int ic = 2*ow - 1 + kw;
                    if (ic < 0) continue;
                    float4 u  = Ug[(b*56 + ih)*56 + ic];
                    float4 wv = *(const float4*)(wg + (kh*3 + kw)*4);
                    a = fmaf(u.x, wv.x, a);
                    a = fmaf(u.y, wv.y, a);
                    a = fmaf(u.z, wv.z, a);
                    a = fmaf(u.w, wv.w, a);
                }
            }
            int k = g*4 + f;
            vs[opx_l*132 + k] = fmaxf(a + t3s[k], 0.f);
        }
    }
    // ---- residual: res[p] = sum_c x[b, 2oh, 2ow, c] ----
    {
        int p = tid >> 4, l = tid & 15;
        int opx = opxBase + p;
        int b = opx / 784, r = opx - b*784;
        int oh = r / 28, ow = r - oh*28;
        const float* xp = x + (size_t)((b*56 + 2*oh)*56 + 2*ow) * 128;
        float rv = 0.f;
        #pragma unroll
        for (int j = 0; j < 8; ++j) rv += xp[l + 16*j];
        #pragma unroll
        for (int off = 8; off; off >>= 1) rv += __shfl_down(rv, off, 16);
        if (l == 0) res_s[p] = rv;
    }
    __syncthreads();

    // ---- phase B: out[opx][co] = vs @ W2 + bsum + res ----
    int w = tid >> 6, l = tid & 63;
    float4 bs = *(const float4*)(tabs + OFF_BSUM + 4*l);
    float acc[4][4];
    #pragma unroll
    for (int qq = 0; qq < 4; ++qq) {
        acc[qq][0] = bs.x; acc[qq][1] = bs.y;
        acc[qq][2] = bs.z; acc[qq][3] = bs.w;
    }
    const float* W2c = W2 + 4*l;
    #pragma unroll 1
    for (int k4 = 0; k4 < 32; ++k4) {
        float4 wr0 = *(const float4*)(W2c + (k4*4 + 0)*256);
        float4 wr1 = *(const float4*)(W2c + (k4*4 + 1)*256);
        float4 wr2 = *(const float4*)(W2c + (k4*4 + 2)*256);
        float4 wr3 = *(const float4*)(W2c + (k4*4 + 3)*256);
        #pragma unroll
        for (int qq = 0; qq < 4; ++qq) {
            float4 v = *(const float4*)&vs[(w*4 + qq)*132 + k4*4];  // broadcast
            acc[qq][0] = fmaf(v.x, wr0.x, acc[qq][0]);
            acc[qq][1] = fmaf(v.x, wr0.y, acc[qq][1]);
            acc[qq][2] = fmaf(v.x, wr0.z, acc[qq][2]);
            acc[qq][3] = fmaf(v.x, wr0.w, acc[qq][3]);
            acc[qq][0] = fmaf(v.y, wr1.x, acc[qq][0]);
            acc[qq][1] = fmaf(v.y, wr1.y, acc[qq][1]);
            acc[qq][2] = fmaf(v.y, wr1.z, acc[qq][2]);
            acc[qq][3] = fmaf(v.y, wr1.w, acc[qq][3]);
            acc[qq][0] = fmaf(v.z, wr2.x, acc[qq][0]);
            acc[qq][1] = fmaf(v.z, wr2.y, acc[qq][1]);
            acc[qq][2] = fmaf(v.z, wr2.z, acc[qq][2]);
            acc[qq][3] = fmaf(v.z, wr2.w, acc[qq][3]);
            acc[qq][0] = fmaf(v.w, wr3.x, acc[qq][0]);
            acc[qq][1] = fmaf(v.w, wr3.y, acc[qq][1]);
            acc[qq][2] = fmaf(v.w, wr3.z, acc[qq][2]);
            acc[qq][3] = fmaf(v.w, wr3.w, acc[qq][3]);
        }
    }
    #pragma unroll
    for (int qq = 0; qq < 4; ++qq) {
        float rq = res_s[w*4 + qq];
        float4 o;
        o.x = acc[qq][0] + rq; o.y = acc[qq][1] + rq;
        o.z = acc[qq][2] + rq; o.w = acc[qq][3] + rq;
        *(float4*)(out + (size_t)(opxBase + w*4 + qq)*256 + 4*l) = o;
    }
}

extern "C" void kernel_launch(void* const* d_in, const int* in_sizes, int n_in,
                              void* d_out, int out_size, void* d_ws, size_t ws_size,
                              hipStream_t stream) {
    const float* x   = (const float*)d_in[0];
    const float* g1  = (const float*)d_in[1];
    const float* be1 = (const float*)d_in[2];
    const float* m1  = (const float*)d_in[3];
    const float* v1  = (const float*)d_in[4];
    const float* W1  = (const float*)d_in[5];
    const float* b1  = (const float*)d_in[6];
    const float* g2  = (const float*)d_in[7];
    const float* be2 = (const float*)d_in[8];
    const float* m2  = (const float*)d_in[9];
    const float* v2  = (const float*)d_in[10];
    const float* W3  = (const float*)d_in[11];
    const float* b3  = (const float*)d_in[12];
    const float* g3  = (const float*)d_in[13];
    const float* be3 = (const float*)d_in[14];
    const float* m3  = (const float*)d_in[15];
    const float* v3  = (const float*)d_in[16];
    const float* W2  = (const float*)d_in[17];
    const float* b2  = (const float*)d_in[18];
    float* out = (float*)d_out;
    float* ws  = (float*)d_ws;

    prep_kernel<<<32, 256, 0, stream>>>(g1, be1, m1, v1, b1, g2, be2, m2, v2,
                                        W3, b3, g3, be3, m3, v3, b2, ws);
    stage1_kernel<<<NPIX / 64, 512, 0, stream>>>(x, W1, ws, ws + OFF_U);
    stage2_kernel<<<NOPIX / 16, 256, 0, stream>>>(x, W2, ws, ws + OFF_U, out);
}